// Round 8
// baseline (384.146 us; speedup 1.0000x reference)
//
#include <hip/hip_runtime.h>
#include <stdint.h>

// Gaussian kernel matrix K[i][j] = exp(-||x_i-x_j||^2/2), X: [16384][64] fp32.
// R8: store-span theory. Evidence: span/row-visit 64B->316us (R2), 128B->266
// (R7), 256B->224 (R6). Block = 64 rows x 256 cols, 4 waves side by side
// (per-wave structure identical to R6). All 4 waves write exp results to a
// SHARED 64x260f LDS buffer; after a raw s_barrier (lgkmcnt(0) only — no
// vmcnt drain!), each wave stores 16 rows as ONE 1KB-contiguous instr each.
// Kept from R6: inline f32->bf16 cvt + norm fusion, B prefetch issued BEFORE
// stores (vmcnt FIFO decoupling), VMEM-only sched_barrier, uniform diagonal
// branch.

typedef __attribute__((ext_vector_type(8))) short s16x8;   // 8 bf16 (MFMA A/B frag)
typedef __attribute__((ext_vector_type(4))) float f32x4;

#define DDIM 64
#define JT 8
#define LROW 260  // LDS row stride in floats (256 data + 4 pad; 1040B: 16B-aligned,
                  // stride = 4 banks -> both LDS phases at the 8-slot/bank floor)
#define LOG2E      1.4426950408889634f   // 2c
#define HALF_LOG2E 0.7213475204444817f   // c ; K = exp2(-c||i||^2 - c||j||^2 + 2c dot)

// fp32 -> bf16 RNE on the bit pattern; accumulates rounded value^2 for norms.
__device__ inline short cvt1(float x, float& sq) {
  uint32_t u = __builtin_bit_cast(uint32_t, x);
  uint32_t r = (u + 0x7fffu + ((u >> 16) & 1u)) & 0xffff0000u;
  float hf = __builtin_bit_cast(float, r);
  sq += hf * hf;
  return (short)(r >> 16);
}

// Issue the 4 dwordx4 loads for one fragment row. Raw loads only.
__device__ inline void issue_row(const float* __restrict__ X, int row, int lq,
                                 f32x4 r[4]) {
  const f32x4* p = reinterpret_cast<const f32x4*>(X + (size_t)row * DDIM + lq * 8);
  const f32x4* q = reinterpret_cast<const f32x4*>(X + (size_t)row * DDIM + 32 + lq * 8);
  r[0] = p[0]; r[1] = p[1]; r[2] = q[0]; r[3] = q[1];
}

// Raw f32 row data -> bf16 MFMA fragments + premultiplied norm (-c*||x||^2).
__device__ inline void cvt_row(const f32x4 r[4], s16x8 h[2], float& hnorm) {
  float s = 0.f;
#pragma unroll
  for (int ks = 0; ks < 2; ++ks) {
    s16x8 hh;
    hh[0] = cvt1(r[2*ks][0], s);   hh[1] = cvt1(r[2*ks][1], s);
    hh[2] = cvt1(r[2*ks][2], s);   hh[3] = cvt1(r[2*ks][3], s);
    hh[4] = cvt1(r[2*ks+1][0], s); hh[5] = cvt1(r[2*ks+1][1], s);
    hh[6] = cvt1(r[2*ks+1][2], s); hh[7] = cvt1(r[2*ks+1][3], s);
    h[ks] = hh;
  }
  s += __shfl_xor(s, 16);
  s += __shfl_xor(s, 32);
  hnorm = -HALF_LOG2E * s;
}

__global__ __launch_bounds__(256, 2) void gauss_gram_kernel(
    const float* __restrict__ X, float* __restrict__ K, int n) {
  const int lane = threadIdx.x & 63;
  const int wid  = threadIdx.x >> 6;   // 4 waves side by side: wave w = cols [w*64, w*64+64)
  const int l15 = lane & 15;
  const int lq  = lane >> 4;           // 0..3

  // Shared transpose buffer: 64 rows x LROW floats, all 4 waves cooperate.
  __shared__ float sbuf[64 * LROW];

  const int i0     = blockIdx.x * 64;          // block's 64 output rows
  const int jstrip = blockIdx.y * (256 * JT);  // 2048-col strip
  const int jw     = wid * 64;                 // this wave's col offset in tile

  // ---- prologue: issue A loads, then B(jt=0) loads; cvt A while B flies ----
  f32x4 araw[4][4];
#pragma unroll
  for (int mi = 0; mi < 4; ++mi)
    issue_row(X, i0 + mi * 16 + l15, lq, araw[mi]);

  f32x4 braw[4][4];
#pragma unroll
  for (int ni = 0; ni < 4; ++ni)
    issue_row(X, jstrip + jw + ni * 16 + l15, lq, braw[ni]);

  s16x8 a[4][2]; float hA[4];
#pragma unroll
  for (int mi = 0; mi < 4; ++mi)
    cvt_row(araw[mi], a[mi], hA[mi]);
  // hA[mi] at lane l is -c*||row (i0+mi*16+l15)||^2 == this lane's output row.

#pragma unroll
  for (int jt = 0; jt < JT; ++jt) {
    const int jtile = jstrip + jt * 256;       // block's 256-col tile base
    const int j0    = jtile + jw;              // this wave's 64 cols

    // ---- cvt current B (waits only on braw loads, older than any stores) ----
    s16x8 b[4][2]; float hcol[4][4];
#pragma unroll
    for (int ni = 0; ni < 4; ++ni) {
      float hB;
      cvt_row(braw[ni], b[ni], hB);
#pragma unroll
      for (int r = 0; r < 4; ++r)
        hcol[ni][r] = __shfl(hB, lq * 4 + r);   // -c*norm of col j0+ni*16+lq*4+r
    }

    // ---- prefetch next tile's B (issued ahead of this tile's stores) ----
    if (jt + 1 < JT) {
#pragma unroll
      for (int ni = 0; ni < 4; ++ni)
        issue_row(X, jstrip + (jt + 1) * 256 + jw + ni * 16 + l15, lq, braw[ni]);
    }
    // Pin VMEM order only: prefetch loads stay above the stores below.
    __builtin_amdgcn_sched_barrier(0x1 | 0x2 | 0x4 | 0x8);

    // ---- MFMA, swapped operands: lane's 4 acc regs = 4 consecutive cols ----
    f32x4 acc[4][4] = {};
#pragma unroll
    for (int ks = 0; ks < 2; ++ks)
#pragma unroll
      for (int mi = 0; mi < 4; ++mi)
#pragma unroll
        for (int ni = 0; ni < 4; ++ni)
          acc[mi][ni] = __builtin_amdgcn_mfma_f32_16x16x32_bf16(
              b[ni][ks], a[mi][ks], acc[mi][ni], 0, 0, 0);

    // Does this wave's 64x64 sub-tile touch the diagonal? (uniform branch)
    const bool diag = (i0 < j0 + 64) && (j0 < i0 + 64);

    // ---- exp + ds_write into the shared 64x256 tile image ----
#pragma unroll
    for (int mi = 0; mi < 4; ++mi) {
      const int rg = i0 + mi * 16 + l15;
#pragma unroll
      for (int ni = 0; ni < 4; ++ni) {
        const int c0 = j0 + ni * 16 + lq * 4;
        f32x4 v;
        if (diag) {
#pragma unroll
          for (int r = 0; r < 4; ++r) {
            float e = exp2f(hA[mi] + hcol[ni][r] + LOG2E * acc[mi][ni][r]);
            v[r] = (rg == c0 + r) ? 1.0f : e;   // exact diagonal
          }
        } else {
#pragma unroll
          for (int r = 0; r < 4; ++r)
            v[r] = exp2f(hA[mi] + hcol[ni][r] + LOG2E * acc[mi][ni][r]);
        }
        *reinterpret_cast<f32x4*>(
            sbuf + (mi * 16 + l15) * LROW + jw + ni * 16 + lq * 4) = v;
      }
    }

    // ---- raw barrier: drain LDS writes only (NOT vmcnt — stores stay in flight) ----
    asm volatile("s_waitcnt lgkmcnt(0)" ::: "memory");
    __builtin_amdgcn_s_barrier();

    // ---- store phase: wave w stores rows [w*16, w*16+16), 1KB contiguous each ----
#pragma unroll
    for (int r = 0; r < 16; ++r) {
      const int row = wid * 16 + r;
      f32x4 t = *reinterpret_cast<const f32x4*>(sbuf + row * LROW + lane * 4);
      *reinterpret_cast<f32x4*>(K + (size_t)(i0 + row) * n + jtile + lane * 4) = t;
    }

    // ---- raw barrier: all waves' ds_reads drained before next tile's writes ----
    asm volatile("s_waitcnt lgkmcnt(0)" ::: "memory");
    __builtin_amdgcn_s_barrier();
  }
}

extern "C" void kernel_launch(void* const* d_in, const int* in_sizes, int n_in,
                              void* d_out, int out_size, void* d_ws, size_t ws_size,
                              hipStream_t stream) {
  (void)n_in; (void)d_ws; (void)ws_size; (void)out_size;
  const float* X = (const float*)d_in[0];
  float* K = (float*)d_out;
  const int n = in_sizes[0] / DDIM;          // 16384
  dim3 grid(n / 64, n / (256 * JT));         // (256, 8)
  gauss_gram_kernel<<<grid, 256, 0, stream>>>(X, K, n);
}

// Round 9
// 225.508 us; speedup vs baseline: 1.7035x; 1.7035x over previous
//
#include <hip/hip_runtime.h>
#include <stdint.h>

// Gaussian kernel matrix K[i][j] = exp(-||x_i-x_j||^2/2), X: [16384][64] fp32.
// R9 = R6 (223.9 us) with ONE change: the LDS-transpose store phase emits
// 4-row x 256B-contiguous segments per instruction (was 8-row x 128B), a
// single visit per row per tile. Segment-width ladder so far at constant
// structure: 64B -> 252.7us (R4), 128B -> 223.9us (R6), 256B -> this test.
// Wave-private buffer (no cross-wave barriers — R8's lockstep mistake),
// LROW=68 floats keeps the 4-bank row rotation => both LDS phases at the
// b128 service floor. Everything else identical to R6: inline f32->bf16 cvt
// + norm fusion, B prefetch issued BEFORE stores (vmcnt FIFO decoupling),
// VMEM-only sched_barrier, per-element diagonal select.

typedef __attribute__((ext_vector_type(8))) short s16x8;   // 8 bf16 (MFMA A/B frag)
typedef __attribute__((ext_vector_type(4))) float f32x4;

#define DDIM 64
#define JT 8
#define LROW 68   // LDS row stride in floats (64 data + 4 pad; 272B = 17x16B,
                  // 68 mod 32 = 4 -> 4-bank rotation per row, uniform banking)
#define LOG2E      1.4426950408889634f   // 2c
#define HALF_LOG2E 0.7213475204444817f   // c ; K = exp2(-c||i||^2 - c||j||^2 + 2c dot)

// fp32 -> bf16 RNE on the bit pattern; accumulates rounded value^2 for norms.
__device__ inline short cvt1(float x, float& sq) {
  uint32_t u = __builtin_bit_cast(uint32_t, x);
  uint32_t r = (u + 0x7fffu + ((u >> 16) & 1u)) & 0xffff0000u;
  float hf = __builtin_bit_cast(float, r);
  sq += hf * hf;
  return (short)(r >> 16);
}

// Issue the 4 dwordx4 loads for one fragment row. Raw loads only.
__device__ inline void issue_row(const float* __restrict__ X, int row, int lq,
                                 f32x4 r[4]) {
  const f32x4* p = reinterpret_cast<const f32x4*>(X + (size_t)row * DDIM + lq * 8);
  const f32x4* q = reinterpret_cast<const f32x4*>(X + (size_t)row * DDIM + 32 + lq * 8);
  r[0] = p[0]; r[1] = p[1]; r[2] = q[0]; r[3] = q[1];
}

// Raw f32 row data -> bf16 MFMA fragments + premultiplied norm (-c*||x||^2).
__device__ inline void cvt_row(const f32x4 r[4], s16x8 h[2], float& hnorm) {
  float s = 0.f;
#pragma unroll
  for (int ks = 0; ks < 2; ++ks) {
    s16x8 hh;
    hh[0] = cvt1(r[2*ks][0], s);   hh[1] = cvt1(r[2*ks][1], s);
    hh[2] = cvt1(r[2*ks][2], s);   hh[3] = cvt1(r[2*ks][3], s);
    hh[4] = cvt1(r[2*ks+1][0], s); hh[5] = cvt1(r[2*ks+1][1], s);
    hh[6] = cvt1(r[2*ks+1][2], s); hh[7] = cvt1(r[2*ks+1][3], s);
    h[ks] = hh;
  }
  s += __shfl_xor(s, 16);
  s += __shfl_xor(s, 32);
  hnorm = -HALF_LOG2E * s;
}

__global__ __launch_bounds__(256, 2) void gauss_gram_kernel(
    const float* __restrict__ X, float* __restrict__ K, int n) {
  const int lane = threadIdx.x & 63;
  const int wid  = threadIdx.x >> 6;   // 4 waves: 2x2 over the 128x128 tile
  const int wr = wid >> 1;
  const int wc = wid & 1;
  const int l15 = lane & 15;
  const int lq  = lane >> 4;           // 0..3
  const int e16 = lane & 15;           // store-phase col chunk (16B each)
  const int r4  = lane >> 4;           // store-phase row within 4-row group

  // Per-wave private transpose buffer: 64 rows x LROW floats (wave-synchronous).
  __shared__ float tbuf[4][64 * LROW];
  float* buf = tbuf[wid];

  const int i0     = blockIdx.x * 128 + wr * 64;   // output row base (this wave)
  const int jstrip = blockIdx.y * (128 * JT);      // column strip base

  // ---- prologue: issue A loads, then B(jt=0) loads; cvt A while B flies ----
  f32x4 araw[4][4];
#pragma unroll
  for (int mi = 0; mi < 4; ++mi)
    issue_row(X, i0 + mi * 16 + l15, lq, araw[mi]);

  f32x4 braw[4][4];
#pragma unroll
  for (int ni = 0; ni < 4; ++ni)
    issue_row(X, jstrip + wc * 64 + ni * 16 + l15, lq, braw[ni]);

  s16x8 a[4][2]; float hA[4];
#pragma unroll
  for (int mi = 0; mi < 4; ++mi)
    cvt_row(araw[mi], a[mi], hA[mi]);
  // hA[mi] at lane l is -c*||row (i0+mi*16+l15)||^2 == this lane's output row.

#pragma unroll
  for (int jt = 0; jt < JT; ++jt) {
    const int j0 = jstrip + jt * 128 + wc * 64;

    // ---- cvt current B (waits only on braw loads, older than any stores) ----
    s16x8 b[4][2]; float hcol[4][4];
#pragma unroll
    for (int ni = 0; ni < 4; ++ni) {
      float hB;
      cvt_row(braw[ni], b[ni], hB);
#pragma unroll
      for (int r = 0; r < 4; ++r)
        hcol[ni][r] = __shfl(hB, lq * 4 + r);   // -c*norm of col j0+ni*16+lq*4+r
    }

    // ---- prefetch next tile's B (issued ahead of this tile's stores) ----
    if (jt + 1 < JT) {
#pragma unroll
      for (int ni = 0; ni < 4; ++ni)
        issue_row(X, jstrip + (jt + 1) * 128 + wc * 64 + ni * 16 + l15, lq, braw[ni]);
    }
    // Pin VMEM order only: prefetch loads stay above the stores below.
    __builtin_amdgcn_sched_barrier(0x1 | 0x2 | 0x4 | 0x8);

    // ---- MFMA, swapped operands: lane's 4 acc regs = 4 consecutive cols ----
    f32x4 acc[4][4] = {};
#pragma unroll
    for (int ks = 0; ks < 2; ++ks)
#pragma unroll
      for (int mi = 0; mi < 4; ++mi)
#pragma unroll
        for (int ni = 0; ni < 4; ++ni)
          acc[mi][ni] = __builtin_amdgcn_mfma_f32_16x16x32_bf16(
              b[ni][ks], a[mi][ks], acc[mi][ni], 0, 0, 0);

    // ---- epilogue: exp -> LDS (whole 64x64 tile image) ----
#pragma unroll
    for (int mi = 0; mi < 4; ++mi) {
      const int rg = i0 + mi * 16 + l15;
#pragma unroll
      for (int ni = 0; ni < 4; ++ni) {
        const int c0 = j0 + ni * 16 + lq * 4;
        f32x4 v;
#pragma unroll
        for (int r = 0; r < 4; ++r) {
          float arg = fminf(hA[mi] + hcol[ni][r] + LOG2E * acc[mi][ni][r], 0.0f);
          float e = exp2f(arg);
          v[r] = (rg == c0 + r) ? 1.0f : e;   // exact diagonal
        }
        *reinterpret_cast<f32x4*>(
            buf + (mi * 16 + l15) * LROW + ni * 16 + lq * 4) = v;
      }
    }

    // ---- store phase: 16 instrs, each 4 rows x 256B contiguous ----
#pragma unroll
    for (int g = 0; g < 16; ++g) {
      const int row = g * 4 + r4;
      f32x4 t = *reinterpret_cast<const f32x4*>(buf + row * LROW + e16 * 4);
      *reinterpret_cast<f32x4*>(
          K + (size_t)(i0 + row) * n + j0 + e16 * 4) = t;
    }
  }
}

extern "C" void kernel_launch(void* const* d_in, const int* in_sizes, int n_in,
                              void* d_out, int out_size, void* d_ws, size_t ws_size,
                              hipStream_t stream) {
  (void)n_in; (void)d_ws; (void)ws_size; (void)out_size;
  const float* X = (const float*)d_in[0];
  float* K = (float*)d_out;
  const int n = in_sizes[0] / DDIM;          // 16384
  dim3 grid(n / 128, n / (128 * JT));        // (128, 16)
  gauss_gram_kernel<<<grid, 256, 0, stream>>>(X, K, n);
}